// Round 2
// baseline (744.561 us; speedup 1.0000x reference)
//
#include <hip/hip_runtime.h>
#include <hip/hip_bf16.h>
#include <hip/hip_cooperative_groups.h>

namespace cg = cooperative_groups;

// Sinkhorn (L1 cost), n=2048, d=64, eps=100, 10 frozen-on-converge iters.
// Single cooperative kernel: C build + 10x(row pass, col pass) + loss.

#define N 2048
#define EPS 100.0f
#define INV_EPS 0.01f
#define LOG_MU (-7.6246189861593985f)   // log(1/2048)
#define NBLK 256
#define NTHR 512
#define NITER 10

__global__ __launch_bounds__(NTHR, 1) void sinkhorn_all(
    const float* __restrict__ A, const float* __restrict__ B,
    float* __restrict__ C,         // [N][N]
    float* __restrict__ u_new_g,   // [N]
    float* __restrict__ part,      // [8][N] col partials
    float* __restrict__ err_part,  // [NBLK]
    float* __restrict__ losspart,  // [NBLK]
    float* __restrict__ out) {
  cg::grid_group grid = cg::this_grid();
  const int tid = threadIdx.x;
  const int bid = blockIdx.x;
  const int w = tid >> 6;     // wave 0..7
  const int lane = tid & 63;

  __shared__ float As[64][68];   // transposed: As[k][i], stride 68 (float4-aligned)
  __shared__ float Bs[64][68];
  __shared__ float vc[N];        // committed v (replicated, bitwise-identical per block)
  __shared__ float uc[8];        // committed u for this block's 8 rows
  __shared__ float red[256];
  __shared__ float sh8[8][64];
  __shared__ float errw[8];

  // ---------------- Phase 0: C[i][j] = sum_k |A[i][k]-B[j][k]| ----------------
  {
    const int ty = tid >> 5;     // 0..15 -> 4 rows each
    const int tx = tid & 31;     // 0..31 -> 2 cols each
    for (int t = 0; t < 4; ++t) {
      int tile = bid * 4 + t;                 // 1024 tiles of 64x64
      int i0 = (tile >> 5) << 6;
      int j0 = (tile & 31) << 6;
      #pragma unroll
      for (int e = 0; e < 8; ++e) {
        int idx = e * NTHR + tid;
        int r = idx >> 6, k = idx & 63;
        As[k][r] = A[(i0 + r) * 64 + k];      // global coalesced; LDS write 8-way (one-time)
        Bs[k][r] = B[(j0 + r) * 64 + k];
      }
      __syncthreads();
      float a00=0,a01=0,a10=0,a11=0,a20=0,a21=0,a30=0,a31=0;
      #pragma unroll 8
      for (int k = 0; k < 64; ++k) {
        float4 av = *(const float4*)&As[k][4*ty];
        float2 bv = *(const float2*)&Bs[k][2*tx];
        a00 += fabsf(av.x - bv.x); a01 += fabsf(av.x - bv.y);
        a10 += fabsf(av.y - bv.x); a11 += fabsf(av.y - bv.y);
        a20 += fabsf(av.z - bv.x); a21 += fabsf(av.z - bv.y);
        a30 += fabsf(av.w - bv.x); a31 += fabsf(av.w - bv.y);
      }
      size_t cb = (size_t)(i0 + 4*ty) * N + j0 + 2*tx;
      *(float2*)&C[cb]           = make_float2(a00, a01);
      *(float2*)&C[cb + N]       = make_float2(a10, a11);
      *(float2*)&C[cb + 2*(size_t)N] = make_float2(a20, a21);
      *(float2*)&C[cb + 3*(size_t)N] = make_float2(a30, a31);
      __syncthreads();
    }
  }

  // init committed state
  for (int j = tid; j < N; j += NTHR) vc[j] = 0.f;
  if (tid < 8) uc[tid] = 0.f;
  bool d_cur = false;   // done entering current iteration (uniform across all threads/blocks)
  __syncthreads();
  grid.sync();

  for (int it = 0; it < NITER; ++it) {
    // ---- Phase A: finish iter it-1 (v commit, done update), then row pass of iter it ----
    if (it > 0) {
      if (tid < 256) red[tid] = err_part[tid];
      __syncthreads();
      #pragma unroll
      for (int s = 128; s > 0; s >>= 1) {
        if (tid < s) red[tid] += red[tid + s];
        __syncthreads();
      }
      float err_prev = red[0];            // identical in every block (fixed tree order)
      bool d_prev = d_cur;                // done entering iter it-1
      for (int j = tid; j < N; j += NTHR) {
        float s = part[j] + part[N + j] + part[2*N + j] + part[3*N + j]
                + part[4*N + j] + part[5*N + j] + part[6*N + j] + part[7*N + j];
        float vn = EPS * (LOG_MU - logf(s + 1e-6f)) + vc[j];
        vc[j] = d_prev ? vc[j] : vn;      // commit v_new_{it-1} with done entering it-1
      }
      d_cur = d_prev || (err_prev < 0.1f);  // done entering iter it
      __syncthreads();
    }
    // row pass: wave w owns row r = 8*bid + w
    {
      int r = bid * 8 + w;
      float ui = uc[w];
      const float* Crow = C + (size_t)r * N;
      float s0 = 0.f, s1 = 0.f;
      #pragma unroll 2
      for (int j4 = lane * 4; j4 < N; j4 += 256) {
        float4 c4 = *(const float4*)&Crow[j4];
        float4 v4 = *(const float4*)&vc[j4];
        s0 += expf((ui + v4.x - c4.x) * INV_EPS);
        s1 += expf((ui + v4.y - c4.y) * INV_EPS);
        s0 += expf((ui + v4.z - c4.z) * INV_EPS);
        s1 += expf((ui + v4.w - c4.w) * INV_EPS);
      }
      float s = s0 + s1;
      #pragma unroll
      for (int off = 32; off > 0; off >>= 1) s += __shfl_down(s, off, 64);
      if (lane == 0) {
        float unew = EPS * (LOG_MU - logf(s + 1e-6f)) + ui;
        u_new_g[r] = unew;
        errw[w] = fabsf(unew - ui);
        uc[w] = d_cur ? ui : unew;        // commit u_new_it with done entering it
      }
      __syncthreads();
      if (tid == 0) {
        float e = 0.f;
        #pragma unroll
        for (int q = 0; q < 8; ++q) e += errw[q];
        err_part[bid] = e;
      }
    }
    grid.sync();

    // ---- Phase B: col partials (uses u_new_it + v entering it) ----
    {
      int jt = bid & 31, rt = bid >> 5;
      int j = jt * 64 + lane;
      float vj = vc[j];
      float s = 0.f;
      int ibase = rt * 256;
      #pragma unroll 4
      for (int ii = w; ii < 256; ii += 8) {
        int i = ibase + ii;
        s += expf((u_new_g[i] + vj - C[(size_t)i * N + j]) * INV_EPS);
      }
      sh8[w][lane] = s;
      __syncthreads();
      if (tid < 64) {
        float t2 = sh8[0][tid] + sh8[1][tid] + sh8[2][tid] + sh8[3][tid]
                 + sh8[4][tid] + sh8[5][tid] + sh8[6][tid] + sh8[7][tid];
        part[rt * N + jt * 64 + tid] = t2;
      }
      __syncthreads();
    }
    grid.sync();
  }

  // ---- wrap-up: commit v_new_9 (uses done entering iter 9) ----
  {
    bool d_prev = d_cur;
    for (int j = tid; j < N; j += NTHR) {
      float s = part[j] + part[N + j] + part[2*N + j] + part[3*N + j]
              + part[4*N + j] + part[5*N + j] + part[6*N + j] + part[7*N + j];
      float vn = EPS * (LOG_MU - logf(s + 1e-6f)) + vc[j];
      vc[j] = d_prev ? vc[j] : vn;
    }
    __syncthreads();
  }

  // ---- loss: sum exp((u_i+v_j-C)/eps) * C ----
  {
    int r = bid * 8 + w;
    float ui = uc[w];
    const float* Crow = C + (size_t)r * N;
    float s0 = 0.f, s1 = 0.f;
    #pragma unroll 2
    for (int j4 = lane * 4; j4 < N; j4 += 256) {
      float4 c4 = *(const float4*)&Crow[j4];
      float4 v4 = *(const float4*)&vc[j4];
      s0 += expf((ui + v4.x - c4.x) * INV_EPS) * c4.x;
      s1 += expf((ui + v4.y - c4.y) * INV_EPS) * c4.y;
      s0 += expf((ui + v4.z - c4.z) * INV_EPS) * c4.z;
      s1 += expf((ui + v4.w - c4.w) * INV_EPS) * c4.w;
    }
    float s = s0 + s1;
    #pragma unroll
    for (int off = 32; off > 0; off >>= 1) s += __shfl_down(s, off, 64);
    if (lane == 0) errw[w] = s;
    __syncthreads();
    if (tid == 0) {
      float e = 0.f;
      #pragma unroll
      for (int q = 0; q < 8; ++q) e += errw[q];
      losspart[bid] = e;
    }
  }
  grid.sync();
  if (bid == 0) {
    if (tid < 256) red[tid] = losspart[tid];
    __syncthreads();
    #pragma unroll
    for (int s = 128; s > 0; s >>= 1) {
      if (tid < s) red[tid] += red[tid + s];
      __syncthreads();
    }
    if (tid == 0) out[0] = red[0];
  }
}

extern "C" void kernel_launch(void* const* d_in, const int* in_sizes, int n_in,
                              void* d_out, int out_size, void* d_ws, size_t ws_size,
                              hipStream_t stream) {
  const float* A = (const float*)d_in[0];
  const float* B = (const float*)d_in[1];
  float* out = (float*)d_out;

  char* base = (char*)d_ws;
  float* C        = (float*)base;                          // 16 MiB
  float* u_new_g  = (float*)(base + (size_t)N * N * 4);
  float* part     = u_new_g + N;                           // 8*N
  float* err_part = part + 8 * N;                          // NBLK
  float* losspart = err_part + NBLK;                       // NBLK
  // (out written directly)

  void* args[] = { (void*)&A, (void*)&B, (void*)&C, (void*)&u_new_g,
                   (void*)&part, (void*)&err_part, (void*)&losspart, (void*)&out };
  hipLaunchCooperativeKernel((const void*)sinkhorn_all,
                             dim3(NBLK), dim3(NTHR), args, 0, stream);
}